// Round 1
// baseline (176.436 us; speedup 1.0000x reference)
//
#include <hip/hip_runtime.h>

namespace {
constexpr int kB = 4;
constexpr int kN = 4096;   // source points per batch
constexpr int kM = 4096;   // target points per batch
constexpr int kBlk = 256;
constexpr int kSplit = 4;              // blocks splitting the inner loop
constexpr int kChunk = kM / kSplit;    // 1024 inner iterations per block
constexpr int kMinCount = 2 * kB * kN; // s2t mins then t2s mins
}

// Init workspace mins to +huge (0x7f7f7f7f = 3.39e38f) and zero the output
// accumulator. Cannot rely on prior contents: harness poisons ws/out to 0xAA.
__global__ __launch_bounds__(kBlk) void cham_init_kernel(unsigned int* mins,
                                                         float* out) {
  int i = blockIdx.x * kBlk + threadIdx.x;
  if (i < kMinCount) mins[i] = 0x7f7f7f7fu;
  if (i == 0) out[0] = 0.0f;
}

// Each thread owns one point of set "own" (registers), scans a kChunk-sized
// slice of set "oth". Inner-loop addresses are wave-uniform -> scalar loads.
// blockIdx.z selects direction (0: source->target, 1: target->source).
__global__ __launch_bounds__(kBlk) void cham_min_kernel(
    const float* __restrict__ src, const float* __restrict__ tgt,
    unsigned int* __restrict__ mins) {
  const int dir = blockIdx.z;
  const float* __restrict__ own = dir ? tgt : src;
  const float* __restrict__ oth = dir ? src : tgt;
  unsigned int* __restrict__ outm = mins + (size_t)dir * kB * kN;

  const int b = blockIdx.y;
  const int chunk = blockIdx.x % kSplit;
  const int nblk = blockIdx.x / kSplit;
  const int n = nblk * kBlk + threadIdx.x;

  const float* p = own + ((size_t)b * kN + n) * 3;
  const float sx = p[0], sy = p[1], sz = p[2];

  const float* __restrict__ q = oth + ((size_t)b * kM + chunk * kChunk) * 3;

  float best = 3.4e38f;
#pragma unroll 8
  for (int m = 0; m < kChunk; ++m) {
    const float dx = sx - q[3 * m + 0];
    const float dy = sy - q[3 * m + 1];
    const float dz = sz - q[3 * m + 2];
    const float d = fmaf(dx, dx, fmaf(dy, dy, dz * dz));
    best = fminf(best, d);
  }

  // Distances are >= 0, so positive-float ordering == unsigned ordering.
  atomicMin(&outm[b * kN + n], __float_as_uint(best));
}

// Sum all 2*B*N per-point mins and scale. mean_b[mean_n(s2t)+mean_m(t2s)]
// == (sum of everything) / (B*N) since N == M.
__global__ __launch_bounds__(kBlk) void cham_reduce_kernel(
    const float* __restrict__ mins, float* __restrict__ out) {
  __shared__ float red[kBlk];
  float acc = 0.0f;
  for (int i = blockIdx.x * kBlk + threadIdx.x; i < kMinCount;
       i += gridDim.x * kBlk)
    acc += mins[i];
  red[threadIdx.x] = acc;
  __syncthreads();
  for (int s = kBlk / 2; s > 0; s >>= 1) {
    if (threadIdx.x < s) red[threadIdx.x] += red[threadIdx.x + s];
    __syncthreads();
  }
  if (threadIdx.x == 0) atomicAdd(out, red[0] * (1.0f / (kB * kN)));
}

extern "C" void kernel_launch(void* const* d_in, const int* in_sizes, int n_in,
                              void* d_out, int out_size, void* d_ws,
                              size_t ws_size, hipStream_t stream) {
  const float* src = (const float*)d_in[0];  // (B, N, 3) fp32
  const float* tgt = (const float*)d_in[1];  // (B, M, 3) fp32
  float* out = (float*)d_out;                // scalar fp32
  unsigned int* mins = (unsigned int*)d_ws;  // 2*B*N uints = 128 KB

  cham_init_kernel<<<dim3((kMinCount + kBlk - 1) / kBlk), kBlk, 0, stream>>>(
      mins, out);

  dim3 grid(kN / kBlk * kSplit, kB, 2);  // (64, 4, 2) = 512 blocks
  cham_min_kernel<<<grid, kBlk, 0, stream>>>(src, tgt, mins);

  cham_reduce_kernel<<<dim3(32), kBlk, 0, stream>>>((const float*)mins, out);
}

// Round 2
// 76.279 us; speedup vs baseline: 2.3130x; 2.3130x over previous
//
#include <hip/hip_runtime.h>

namespace {
constexpr int kB = 4;
constexpr int kN = 4096;              // points per set per batch (N == M)
constexpr int kP = 2 * kB * kN;       // total points across both sets = 32768
constexpr int kBlk = 256;
constexpr int kSplit = 16;            // inner-loop split (blocks per point-tile)
constexpr int kChunk = kN / kSplit;   // 256 inner iterations per block
}

// ws layout:
//   [0 .. kP) uint32            : per-point min keys (monotone-mapped floats)
//   [kP*4 .. kP*4 + kP*16) f4   : packed points (x, y, z, ||p||^2)
//     pack[0 .. B*N)            : target points  (the "other" set for dir 0)
//     pack[B*N .. 2*B*N)        : source points  (the "other" set for dir 1)

// Monotone float->uint map so unsigned atomicMin orders ALL floats (partial
// e = ||y||^2 - 2 x.y can be negative). encode: f>=0 -> u|msb ; f<0 -> ~u.
__device__ __forceinline__ unsigned enc(float f) {
  unsigned u = __float_as_uint(f);
  return (u & 0x80000000u) ? ~u : (u | 0x80000000u);
}
__device__ __forceinline__ float dec(unsigned k) {
  return __uint_as_float((k & 0x80000000u) ? (k ^ 0x80000000u) : ~k);
}

// Pack every point as (x, y, z, ||p||^2), init keys to +max, zero the output.
__global__ __launch_bounds__(kBlk) void cham_prep_kernel(
    const float* __restrict__ src, const float* __restrict__ tgt,
    float4* __restrict__ pack, unsigned int* __restrict__ keys,
    float* __restrict__ out) {
  int i = blockIdx.x * kBlk + threadIdx.x;
  if (i < kP) {
    const float* p = (i < kB * kN) ? (tgt + (size_t)i * 3)
                                   : (src + (size_t)(i - kB * kN) * 3);
    float x = p[0], y = p[1], z = p[2];
    pack[i] = make_float4(x, y, z, fmaf(x, x, fmaf(y, y, z * z)));
    keys[i] = 0xFFFFFFFFu;  // encodes "largest possible" for atomicMin
  }
  if (i == 0 && blockIdx.x == 0) out[0] = 0.0f;
}

// One thread = one "own" point; scans a kChunk slice of the "other" set.
// min_y ||x-y||^2 = ||x||^2 + min_y (||y||^2 - 2 x.y): inner pair costs
// 1 s_load_dwordx4 (wave-uniform addr -> scalar pipe) + 3 v_fma + 1 v_min.
__global__ __launch_bounds__(kBlk) void cham_min_kernel(
    const float4* __restrict__ pack, unsigned int* __restrict__ keys) {
  const int dir = blockIdx.z;                     // 0: s->t, 1: t->s
  const int b = blockIdx.y;
  const int chunk = blockIdx.x & (kSplit - 1);
  const int ntile = blockIdx.x / kSplit;
  const int n = ntile * kBlk + threadIdx.x;

  // dir 0: own = source (second half of pack), other = target (first half)
  const float4* __restrict__ own = pack + (size_t)(dir ^ 1) * kB * kN;
  const float4* __restrict__ oth = pack + (size_t)dir * kB * kN;

  const float4 v = own[(size_t)b * kN + n];       // coalesced per-lane load
  const float nx = -2.0f * v.x, ny = -2.0f * v.y, nz = -2.0f * v.z;

  const float4* __restrict__ q = oth + (size_t)b * kN + chunk * kChunk;

  float e0 = 3.4e38f, e1 = 3.4e38f, e2 = 3.4e38f, e3 = 3.4e38f;
#pragma unroll 4
  for (int m = 0; m < kChunk; m += 4) {
    float4 a = q[m + 0];
    float4 bb = q[m + 1];
    float4 c = q[m + 2];
    float4 d = q[m + 3];
    e0 = fminf(e0, fmaf(nx, a.x, fmaf(ny, a.y, fmaf(nz, a.z, a.w))));
    e1 = fminf(e1, fmaf(nx, bb.x, fmaf(ny, bb.y, fmaf(nz, bb.z, bb.w))));
    e2 = fminf(e2, fmaf(nx, c.x, fmaf(ny, c.y, fmaf(nz, c.z, c.w))));
    e3 = fminf(e3, fmaf(nx, d.x, fmaf(ny, d.y, fmaf(nz, d.z, d.w))));
  }

  float best = fminf(fminf(e0, e1), fminf(e2, e3)) + v.w;
  atomicMin(&keys[((size_t)dir * kB + b) * kN + n], enc(best));
}

// Decode keys, sum all 2*B*N per-point mins, scale by 1/(B*N) (N == M).
__global__ __launch_bounds__(kBlk) void cham_reduce_kernel(
    const unsigned int* __restrict__ keys, float* __restrict__ out) {
  __shared__ float red[kBlk];
  float acc = 0.0f;
  for (int i = blockIdx.x * kBlk + threadIdx.x; i < kP; i += gridDim.x * kBlk)
    acc += dec(keys[i]);
  red[threadIdx.x] = acc;
  __syncthreads();
  for (int s = kBlk / 2; s > 0; s >>= 1) {
    if (threadIdx.x < s) red[threadIdx.x] += red[threadIdx.x + s];
    __syncthreads();
  }
  if (threadIdx.x == 0) atomicAdd(out, red[0] * (1.0f / (kB * kN)));
}

extern "C" void kernel_launch(void* const* d_in, const int* in_sizes, int n_in,
                              void* d_out, int out_size, void* d_ws,
                              size_t ws_size, hipStream_t stream) {
  const float* src = (const float*)d_in[0];  // (B, N, 3) fp32
  const float* tgt = (const float*)d_in[1];  // (B, M, 3) fp32
  float* out = (float*)d_out;                // scalar fp32

  unsigned int* keys = (unsigned int*)d_ws;              // 128 KB
  float4* pack = (float4*)((char*)d_ws + (size_t)kP * 4);  // 512 KB, 16B-aligned

  cham_prep_kernel<<<dim3(kP / kBlk), kBlk, 0, stream>>>(src, tgt, pack, keys,
                                                         out);

  // (16 tiles * 16 splits, B, 2 dirs) = 2048 blocks -> 8 blocks/CU, 32 waves/CU
  dim3 grid(kN / kBlk * kSplit, kB, 2);
  cham_min_kernel<<<grid, kBlk, 0, stream>>>(pack, keys);

  cham_reduce_kernel<<<dim3(32), kBlk, 0, stream>>>(keys, out);
}